// Round 7
// baseline (1693.946 us; speedup 1.0000x reference)
//
#include <hip/hip_runtime.h>
#include <hip/hip_bf16.h>
#include <stdint.h>

// ---------------------------------------------------------------------------
// ViT encoder (4 shared layers) for MI355X. Dtype-agnostic ingest, fp32
// residual stream in ws, bf16 MFMA (16x16x32) everywhere.
// R4: XOR-swizzled LDS staging + XCD-slab mapping (conflicts -> 0).
// R5: BK=64 (32 MFMA per barrier drain).
// R6: JT=8 wide tiles REGRESSED (occupancy cliff) -> reverted.
// R7: single-barrier double-buffered K-loop: stage(k+1) issued right after
//     the barrier, drained by the NEXT barrier a full compute phase later.
// ---------------------------------------------------------------------------

typedef __attribute__((ext_vector_type(8))) short bf16x8;   // 8 bf16 = 4 VGPRs
typedef __attribute__((ext_vector_type(4))) short bf16x4;   // 8 bytes
typedef __attribute__((ext_vector_type(4))) float f32x4;

#define LOG2E 1.44269504088896340736f

typedef const __attribute__((address_space(1))) uint32_t gas_u32;
typedef __attribute__((address_space(3))) uint32_t las_u32;

__device__ __forceinline__ void gld_lds16(const void* g, void* l) {
  __builtin_amdgcn_global_load_lds((gas_u32*)g, (las_u32*)l, 16, 0, 0);
}

__device__ __forceinline__ bf16x8 lds_read8u(const __hip_bfloat16* p) {
  union { bf16x4 h[2]; bf16x8 v; } u;
  u.h[0] = *(const bf16x4*)p;
  u.h[1] = *(const bf16x4*)(p + 4);
  return u.v;
}

// flag-aware raw-input load: bf==1 -> bf16 stream, bf==0 -> fp32 stream
__device__ __forceinline__ float ldin(const void* p, size_t i, int bf) {
  return bf ? __bfloat162float(((const __hip_bfloat16*)p)[i])
            : ((const float*)p)[i];
}

__device__ __forceinline__ float4 ldin4(const void* p, size_t i4, int bf) {
  if (bf) {
    union { uint2 u; __hip_bfloat16 e[4]; } v;
    v.u = *(const uint2*)((const __hip_bfloat16*)p + i4 * 4);
    return make_float4(__bfloat162float(v.e[0]), __bfloat162float(v.e[1]),
                       __bfloat162float(v.e[2]), __bfloat162float(v.e[3]));
  }
  return ((const float4*)p)[i4];
}

// ---------------------------------------------------------------------------
// Dtype flag from ln1_g (== ones(768)).
// ---------------------------------------------------------------------------
__global__ void k_flag(const void* __restrict__ g, int* __restrict__ flag) {
  if (threadIdx.x == 0 && blockIdx.x == 0) {
    uint32_t w = *(const uint32_t*)g;
    *flag = ((w & 0xFFFFu) == 0x3F80u) ? 1 : 0;
  }
}

// ---------------------------------------------------------------------------
// Embedding
// ---------------------------------------------------------------------------
__global__ __launch_bounds__(256) void k_embed(
    const void* __restrict__ img, const void* __restrict__ cls,
    const void* __restrict__ pos, float* __restrict__ X,
    const int* __restrict__ dflag)
{
  const int bf = *dflag;
  size_t idx4 = (size_t)blockIdx.x * 256 + threadIdx.x;   // 12608*192 total
  if (idx4 >= (size_t)12608 * 192) return;
  int d4 = (int)(idx4 % 192);
  int row = (int)(idx4 / 192);
  int b = row / 197, s = row % 197;
  float4 base = (s == 0) ? ldin4(cls, d4, bf)
                         : ldin4(img, (size_t)(b * 196 + s - 1) * 192 + d4, bf);
  float4 p = ldin4(pos, (size_t)s * 192 + d4, bf);
  ((float4*)X)[idx4] = make_float4(base.x + p.x, base.y + p.y, base.z + p.z, base.w + p.w);
}

// ---------------------------------------------------------------------------
// Tiled transpose pack
// ---------------------------------------------------------------------------
__global__ __launch_bounds__(256) void k_packT(
    const void* __restrict__ in, __hip_bfloat16* __restrict__ out,
    int K, int N, int NR, const int* __restrict__ dflag)
{
  __shared__ float t[32][33];
  const int bf = *dflag;
  int ktiles = (K + 31) >> 5;
  int k0 = (blockIdx.x % ktiles) << 5;
  int n0 = (blockIdx.x / ktiles) << 5;
  int tx = threadIdx.x & 31, ty = threadIdx.x >> 5;   // 32 x 8
#pragma unroll
  for (int i = 0; i < 32; i += 8) {
    int k = k0 + ty + i, n = n0 + tx;
    t[ty + i][tx] = (k < K && n < N) ? ldin(in, (size_t)k * N + n, bf) : 0.f;
  }
  __syncthreads();
#pragma unroll
  for (int i = 0; i < 32; i += 8) {
    int n = n0 + ty + i, k = k0 + tx;
    if (n < NR && k < K)
      out[(size_t)n * K + k] = __float2bfloat16(t[tx][ty + i]);
  }
}

// ---------------------------------------------------------------------------
// cls-row pack for the head
// ---------------------------------------------------------------------------
__global__ __launch_bounds__(256) void k_packcls(
    const float* __restrict__ X, __hip_bfloat16* __restrict__ xcls)
{
  int idx = blockIdx.x * 256 + threadIdx.x;   // 128*768
  if (idx >= 128 * 768) return;
  int r = idx / 768, d = idx % 768;
  float v = (r < 64) ? X[(size_t)r * 197 * 768 + d] : 0.f;
  xcls[idx] = __float2bfloat16(v);
}

// ---------------------------------------------------------------------------
// LayerNorm
// ---------------------------------------------------------------------------
__global__ __launch_bounds__(256) void k_ln(
    const float* __restrict__ X, const void* __restrict__ g,
    const void* __restrict__ b, __hip_bfloat16* __restrict__ Y, int rows,
    const int* __restrict__ dflag)
{
  const int bf = *dflag;
  int wave = threadIdx.x >> 6, lane = threadIdx.x & 63;
  int row = blockIdx.x * 4 + wave;
  if (row >= rows) return;
  const float4* xr = (const float4*)(X + (size_t)row * 768);
  float4 v[3];
  float s = 0.f;
#pragma unroll
  for (int i = 0; i < 3; i++) {
    v[i] = xr[lane + i * 64];
    s += v[i].x + v[i].y + v[i].z + v[i].w;
  }
#pragma unroll
  for (int m = 1; m < 64; m <<= 1) s += __shfl_xor(s, m, 64);
  float mu = s * (1.f / 768.f);
  float q = 0.f;
#pragma unroll
  for (int i = 0; i < 3; i++) {
    float dx = v[i].x - mu, dy = v[i].y - mu, dz = v[i].z - mu, dw = v[i].w - mu;
    q += dx * dx + dy * dy + dz * dz + dw * dw;
  }
#pragma unroll
  for (int m = 1; m < 64; m <<= 1) q += __shfl_xor(q, m, 64);
  float rs = rsqrtf(q * (1.f / 768.f) + 1e-5f);
  uint2* yr = (uint2*)(Y + (size_t)row * 768);
#pragma unroll
  for (int i = 0; i < 3; i++) {
    int i4 = lane + i * 64;
    float4 gv = ldin4(g, i4, bf);
    float4 bv = ldin4(b, i4, bf);
    union { uint2 u; __hip_bfloat16 e[4]; } o;
    o.e[0] = __float2bfloat16((v[i].x - mu) * rs * gv.x + bv.x);
    o.e[1] = __float2bfloat16((v[i].y - mu) * rs * gv.y + bv.y);
    o.e[2] = __float2bfloat16((v[i].z - mu) * rs * gv.z + bv.z);
    o.e[3] = __float2bfloat16((v[i].w - mu) * rs * gv.w + bv.w);
    yr[i4] = o.u;
  }
}

// ---------------------------------------------------------------------------
// GEMM: C[M][N] = A[M][K] * Bt[N][K]^T.  128x128 block, BK=64,
// double-buffered LDS with ONE barrier per K-iter (prefetch issued right
// after the barrier, drained by the next barrier a compute-phase later).
// XOR-swizzled chunks (conflict-free), XCD-slab mapping.
// EPI 0: bf16; 1: +bias relu bf16; 2: +bias +Res fp32; 3: head
// ORDER 0: bn-outer/bm-inner; 1: bm-outer/bn-inner; 2: legacy linear
// Requires K % 64 == 0.
// ---------------------------------------------------------------------------
template <int EPI, int ORDER>
__global__ __launch_bounds__(256, 2) void k_gemm(
    const __hip_bfloat16* __restrict__ A, const __hip_bfloat16* __restrict__ Bt,
    const void* __restrict__ bias, const float* __restrict__ Res,
    void* __restrict__ Cout, int K, int N, int Mstore, int ntiles, int mtiles,
    const int* __restrict__ dflag)
{
  __shared__ __align__(16) __hip_bfloat16 As[2][128 * 64];   // 2 x 16 KB
  __shared__ __align__(16) __hip_bfloat16 Bs[2][128 * 64];   // 2 x 16 KB

  int bm, bn;
  if (ORDER == 2) {
    bm = blockIdx.x / ntiles; bn = blockIdx.x % ntiles;
  } else {
    const int xcd = blockIdx.x & 7;
    const int i = blockIdx.x >> 3;
    if (ORDER == 0) { bn = i / 13; bm = xcd * 13 + (i % 13); }
    else            { bm = xcd * 13 + i / ntiles; bn = i % ntiles; }
    if (bm >= mtiles) return;
  }

  const int bf = (EPI == 0) ? 0 : *dflag;
  const int tid = threadIdx.x;
  const int m0 = bm * 128, n0 = bn * 128;
  const int wave = tid >> 6, lane = tid & 63;
  const int wm = (wave >> 1) * 64, wn = (wave & 1) * 64;
  const int qd = lane >> 4, l16 = lane & 15;

  // Staging: chunk q covers (row = q>>3, slot c = q&7); global col fetched is
  // c ^ (row&7). Threads cover q = tid + 256*g; (q>>3)&7 == (tid>>3)&7.
  const int r0 = tid >> 3;                                // 0..31
  const int kk0 = (((tid & 7) ^ (r0 & 7))) * 8;
  const __hip_bfloat16* Agp = A + (size_t)(m0 + r0) * K + kk0;
  const __hip_bfloat16* Bgp = Bt + (size_t)(n0 + r0) * K + kk0;

  f32x4 acc[4][4] = {};
  const int nk = K >> 6;

  // prologue: stage tile 0 into buffer 0
#pragma unroll
  for (int g = 0; g < 4; g++) {
    gld_lds16(Agp + (size_t)(32 * g) * K, &As[0][(tid + 256 * g) * 8]);
    gld_lds16(Bgp + (size_t)(32 * g) * K, &Bs[0][(tid + 256 * g) * 8]);
  }
  Agp += 64; Bgp += 64;

  for (int kt = 0; kt < nk; kt++) {
    __syncthreads();   // drains the loads staged one full compute-phase ago
    const int cb = kt & 1;
    if (kt + 1 < nk) {
      const int nb = cb ^ 1;
#pragma unroll
      for (int g = 0; g < 4; g++) {
        gld_lds16(Agp + (size_t)(32 * g) * K, &As[nb][(tid + 256 * g) * 8]);
        gld_lds16(Bgp + (size_t)(32 * g) * K, &Bs[nb][(tid + 256 * g) * 8]);
      }
      Agp += 64; Bgp += 64;
    }
#pragma unroll
    for (int h = 0; h < 2; h++) {          // two 32-wide k-slices
      bf16x8 af[4], bfr[4];
#pragma unroll
      for (int i = 0; i < 4; i++) {
        int row = wm + i * 16 + l16;
        int ch = (h * 4 + qd) ^ (row & 7);
        af[i] = *(const bf16x8*)&As[cb][row * 64 + ch * 8];
      }
#pragma unroll
      for (int j = 0; j < 4; j++) {
        int row = wn + j * 16 + l16;
        int ch = (h * 4 + qd) ^ (row & 7);
        bfr[j] = *(const bf16x8*)&Bs[cb][row * 64 + ch * 8];
      }
#pragma unroll
      for (int i = 0; i < 4; i++)
#pragma unroll
        for (int j = 0; j < 4; j++)
          acc[i][j] = __builtin_amdgcn_mfma_f32_16x16x32_bf16(af[i], bfr[j], acc[i][j], 0, 0, 0);
    }
  }

  // C/D layout: col = lane&15, row = (lane>>4)*4 + reg   [m89-verified]
#pragma unroll
  for (int i = 0; i < 4; i++) {
#pragma unroll
    for (int r = 0; r < 4; r++) {
      int gr = m0 + wm + i * 16 + qd * 4 + r;
      if (gr < Mstore) {
#pragma unroll
        for (int j = 0; j < 4; j++) {
          int gc = n0 + wn + j * 16 + l16;
          float v = acc[i][j][r];
          if (EPI == 0) {
            ((__hip_bfloat16*)Cout)[(size_t)gr * N + gc] = __float2bfloat16(v);
          } else if (EPI == 1) {
            v += ldin(bias, gc, bf);
            v = v > 0.f ? v : 0.f;
            ((__hip_bfloat16*)Cout)[(size_t)gr * N + gc] = __float2bfloat16(v);
          } else if (EPI == 2) {
            v += ldin(bias, gc, bf) + Res[(size_t)gr * N + gc];
            ((float*)Cout)[(size_t)gr * N + gc] = v;
          } else {                       // EPI == 3: head
            if (gc < N) {
              v += ldin(bias, gc, bf);
              if (bf) ((__hip_bfloat16*)Cout)[(size_t)gr * N + gc] = __float2bfloat16(v);
              else    ((float*)Cout)[(size_t)gr * N + gc] = v;
            }
          }
        }
      }
    }
  }
}

// ---------------------------------------------------------------------------
// Fused attention (flash-style) — unchanged.
// ---------------------------------------------------------------------------
__global__ __launch_bounds__(256, 2) void k_attn(
    const __hip_bfloat16* __restrict__ qkv,   // [12608][2304] q|k|v
    const float* __restrict__ X, float* __restrict__ Aout)
{
  const int half = blockIdx.x & 1;
  const int bh = blockIdx.x >> 1;
  const int b = bh / 12, h = bh % 12;
  const size_t tokbase = (size_t)b * 197;

  __shared__ __align__(16) __hip_bfloat16 Ks[128 * 68];      // K[j][d], stride 68
  __shared__ __align__(16) __hip_bfloat16 Vt[64 * 132];      // V^T[d][j], stride 132
  __shared__ __align__(16) __hip_bfloat16 Ps[4][16 * 132];   // per-wave P tile

  const int tid = threadIdx.x;
  const int wave = tid >> 6, lane = tid & 63;
  const int qd = lane >> 4, l16 = lane & 15;

  const int tbase = half * 7;
  const int tcnt = half ? 6 : 7;
  const int mt[2] = { tbase + wave, tbase + wave + 4 };
  const int nmt = (wave + 4 < tcnt) ? 2 : 1;

  f32x4 Ofr[2][4] = {};           // [mtile][dtile], rows = qd*4+reg
  float mrun[2][4], lrun[2][4];
#pragma unroll
  for (int i = 0; i < 2; i++)
#pragma unroll
    for (int r = 0; r < 4; r++) { mrun[i][r] = -1e30f; lrun[i][r] = 0.f; }

  for (int jt = 0; jt < 2; jt++) {
    const int j0 = jt * 128;
    for (int c = tid; c < 128 * 16; c += 256) {
      int j = c >> 4, ch = (c & 15) * 4;
      const __hip_bfloat16* ksrc = qkv + (tokbase + j0 + j) * 2304 + 768 + h * 64 + ch;
      *(uint2*)&Ks[j * 68 + ch] = *(const uint2*)ksrc;
      const __hip_bfloat16* vsrc = qkv + (tokbase + j0 + j) * 2304 + 1536 + h * 64 + ch;
      union { uint2 u; __hip_bfloat16 e[4]; } vv;
      vv.u = *(const uint2*)vsrc;
      bool jvalid = (j0 + j) < 197;
      __hip_bfloat16 zero = __float2bfloat16(0.f);
#pragma unroll
      for (int i = 0; i < 4; i++)
        Vt[(ch + i) * 132 + j] = jvalid ? vv.e[i] : zero;
    }
    __syncthreads();

#pragma unroll
    for (int im = 0; im < 2; im++) {
      if (im < nmt) {
        const int m0 = mt[im] * 16;
        const __hip_bfloat16* qsrc = qkv + (tokbase + m0 + l16) * 2304 + h * 64 + qd * 8;
        bf16x8 qa0 = *(const bf16x8*)qsrc;
        bf16x8 qa1 = *(const bf16x8*)(qsrc + 32);

        f32x4 sc[8];
#pragma unroll
        for (int nt = 0; nt < 8; nt++) {
          bf16x8 kb0 = lds_read8u(&Ks[(nt * 16 + l16) * 68 + qd * 8]);
          bf16x8 kb1 = lds_read8u(&Ks[(nt * 16 + l16) * 68 + 32 + qd * 8]);
          f32x4 t = {0.f, 0.f, 0.f, 0.f};
          t = __builtin_amdgcn_mfma_f32_16x16x32_bf16(qa0, kb0, t, 0, 0, 0);
          sc[nt] = __builtin_amdgcn_mfma_f32_16x16x32_bf16(qa1, kb1, t, 0, 0, 0);
        }

        // ---- online softmax (NaN-sanitized) ----
        float rmax[4];
#pragma unroll
        for (int r = 0; r < 4; r++) rmax[r] = mrun[im][r];
#pragma unroll
        for (int nt = 0; nt < 8; nt++) {
          int col = j0 + nt * 16 + l16;
          bool valid = col < 197;
#pragma unroll
          for (int r = 0; r < 4; r++) {
            float sv = valid ? fminf(fmaxf(sc[nt][r] * 0.125f, -1e30f), 1e30f) : -1e30f;
            sc[nt][r] = sv;
            rmax[r] = fmaxf(rmax[r], sv);
          }
        }
#pragma unroll
        for (int r = 0; r < 4; r++) {
          float v = rmax[r];
          v = fmaxf(v, __shfl_xor(v, 1, 64));
          v = fmaxf(v, __shfl_xor(v, 2, 64));
          v = fmaxf(v, __shfl_xor(v, 4, 64));
          v = fmaxf(v, __shfl_xor(v, 8, 64));
          rmax[r] = v;
        }
        float alpha[4], rsum[4];
#pragma unroll
        for (int r = 0; r < 4; r++) {
          alpha[r] = exp2f((mrun[im][r] - rmax[r]) * LOG2E);
          rsum[r] = 0.f;
        }
#pragma unroll
        for (int nt = 0; nt < 8; nt++) {
#pragma unroll
          for (int r = 0; r < 4; r++) {
            float p = exp2f((sc[nt][r] - rmax[r]) * LOG2E);
            rsum[r] += p;
            Ps[wave][(qd * 4 + r) * 132 + nt * 16 + l16] = __float2bfloat16(p);
          }
        }
#pragma unroll
        for (int r = 0; r < 4; r++) {
          float v = rsum[r];
          v += __shfl_xor(v, 1, 64);
          v += __shfl_xor(v, 2, 64);
          v += __shfl_xor(v, 4, 64);
          v += __shfl_xor(v, 8, 64);
          lrun[im][r] = lrun[im][r] * alpha[r] + v;
          mrun[im][r] = rmax[r];
#pragma unroll
          for (int dt = 0; dt < 4; dt++) Ofr[im][dt][r] *= alpha[r];
        }

#pragma unroll
        for (int kf = 0; kf < 4; kf++) {
          bf16x8 pa = lds_read8u(&Ps[wave][l16 * 132 + kf * 32 + qd * 8]);
#pragma unroll
          for (int dt = 0; dt < 4; dt++) {
            bf16x8 vb = lds_read8u(&Vt[(dt * 16 + l16) * 132 + kf * 32 + qd * 8]);
            Ofr[im][dt] = __builtin_amdgcn_mfma_f32_16x16x32_bf16(pa, vb, Ofr[im][dt], 0, 0, 0);
          }
        }
      }
    }
    __syncthreads();
  }

#pragma unroll
  for (int im = 0; im < 2; im++) {
    if (im < nmt) {
      const int m0 = mt[im] * 16;
#pragma unroll
      for (int r = 0; r < 4; r++) {
        int row = m0 + qd * 4 + r;
        if (row < 197) {
          float inv = 1.f / lrun[im][r];
          size_t gbase = (tokbase + row) * 768 + h * 64;
#pragma unroll
          for (int dt = 0; dt < 4; dt++) {
            int col = dt * 16 + l16;
            Aout[gbase + col] = X[gbase + col] + Ofr[im][dt][r] * inv;
          }
        }
      }
    }
  }
}

// ---------------------------------------------------------------------------
// Workspace layout: unchanged (total 188,157,952 bytes).
// ---------------------------------------------------------------------------
extern "C" void kernel_launch(void* const* d_in, const int* in_sizes, int n_in,
                              void* d_out, int out_size, void* d_ws, size_t ws_size,
                              hipStream_t stream)
{
  const void* image = d_in[0];
  const void* cls   = d_in[1];
  const void* pos   = d_in[2];
  const void* ln1g  = d_in[3];
  const void* ln1b  = d_in[4];
  const void* wq    = d_in[5];
  const void* wk    = d_in[6];
  const void* wv    = d_in[7];
  const void* ln2g  = d_in[8];
  const void* ln2b  = d_in[9];
  const void* w1    = d_in[10];
  const void* b1    = d_in[11];
  const void* w2    = d_in[12];
  const void* b2    = d_in[13];
  const void* hw    = d_in[14];
  const void* hb    = d_in[15];

  if (ws_size < 188157952ull) return;  // not enough scratch -> loud failure

  char* w = (char*)d_ws;
  __hip_bfloat16* xn    = (__hip_bfloat16*)(w);
  __hip_bfloat16* qkv   = (__hip_bfloat16*)(w + 19464192);
  __hip_bfloat16* hid   = qkv;  // disjoint lifetimes
  __hip_bfloat16* hwT   = qkv;  // reused after the loop
  __hip_bfloat16* xcls  = (__hip_bfloat16*)(w + 19464192 + 1572864);
  __hip_bfloat16* wqkvT = (__hip_bfloat16*)(w + 97320960);
  __hip_bfloat16* w1T   = (__hip_bfloat16*)(w + 100859904);
  __hip_bfloat16* w2T   = (__hip_bfloat16*)(w + 105578496);
  float* X              = (float*)(w + 110297088);
  float* A              = (float*)(w + 149225472);
  int* dflag            = (int*)(w + 188153856);

  k_flag<<<1, 64, 0, stream>>>(ln1g, dflag);
  k_packT<<<24 * 24, 256, 0, stream>>>(wq, wqkvT,              768,  768,  768, dflag);
  k_packT<<<24 * 24, 256, 0, stream>>>(wk, wqkvT +  768 * 768, 768,  768,  768, dflag);
  k_packT<<<24 * 24, 256, 0, stream>>>(wv, wqkvT + 1536 * 768, 768,  768,  768, dflag);
  k_packT<<<24 * 96, 256, 0, stream>>>(w1, w1T,                768, 3072, 3072, dflag);
  k_packT<<<96 * 24, 256, 0, stream>>>(w2, w2T,               3072,  768,  768, dflag);
  k_embed<<<9456, 256, 0, stream>>>(image, cls, pos, X, dflag);

  for (int l = 0; l < 4; l++) {
    k_ln<<<3152, 256, 0, stream>>>(X, ln1g, ln1b, xn, 12608, dflag);
    k_gemm<0,0><<<8 * 13 * 18, 256, 0, stream>>>(xn, wqkvT, (const void*)nullptr,
                                           (const float*)nullptr, qkv, 768, 2304, 12608, 18, 99, dflag);
    k_attn<<<1536, 256, 0, stream>>>(qkv, X, A);
    k_ln<<<3152, 256, 0, stream>>>(A, ln2g, ln2b, xn, 12608, dflag);
    k_gemm<1,0><<<8 * 13 * 24, 256, 0, stream>>>(xn, w1T, b1, (const float*)nullptr,
                                           hid, 768, 3072, 12608, 24, 99, dflag);
    k_gemm<2,1><<<8 * 13 * 6, 256, 0, stream>>>(hid, w2T, b2, A, X, 3072, 768, 12608, 6, 99, dflag);
  }

  // classifier head as MFMA GEMM (qkv region is free now)
  k_packT<<<24 * 32, 256, 0, stream>>>(hw, hwT, 768, 1000, 1024, dflag);
  k_packcls<<<384, 256, 0, stream>>>(X, xcls);
  k_gemm<3,2><<<8, 256, 0, stream>>>(xcls, hwT, hb, (const float*)nullptr,
                                   d_out, 768, 1000, 64, 8, 1, dflag);
}

// Round 8
// 1441.703 us; speedup vs baseline: 1.1750x; 1.1750x over previous
//
#include <hip/hip_runtime.h>
#include <hip/hip_bf16.h>
#include <stdint.h>

// ---------------------------------------------------------------------------
// ViT encoder (4 shared layers) for MI355X. Dtype-agnostic ingest, fp32
// residual stream in ws, bf16 MFMA (16x16x32) everywhere.
// R4: XOR-swizzled LDS staging + XCD-slab mapping (conflicts -> 0).
// R5: BK=64, 2-barrier single-buffer loop  <- proven best inner structure
// R6: fat accumulators REGRESSED (VGPR cliff).  R7: dbuf REGRESSED (LDS cliff).
// R8: 512-thread blocks, 128x256 tile, 8 waves x (64x64 sub-tile, 64 AGPR) —
//     more waves/CU (16->24), less staged vmem + fewer barriers per FLOP,
//     with R5's per-wave register footprint untouched.
// ---------------------------------------------------------------------------

typedef __attribute__((ext_vector_type(8))) short bf16x8;   // 8 bf16 = 4 VGPRs
typedef __attribute__((ext_vector_type(4))) short bf16x4;   // 8 bytes
typedef __attribute__((ext_vector_type(4))) float f32x4;

#define LOG2E 1.44269504088896340736f

typedef const __attribute__((address_space(1))) uint32_t gas_u32;
typedef __attribute__((address_space(3))) uint32_t las_u32;

__device__ __forceinline__ void gld_lds16(const void* g, void* l) {
  __builtin_amdgcn_global_load_lds((gas_u32*)g, (las_u32*)l, 16, 0, 0);
}

__device__ __forceinline__ bf16x8 lds_read8u(const __hip_bfloat16* p) {
  union { bf16x4 h[2]; bf16x8 v; } u;
  u.h[0] = *(const bf16x4*)p;
  u.h[1] = *(const bf16x4*)(p + 4);
  return u.v;
}

// flag-aware raw-input load: bf==1 -> bf16 stream, bf==0 -> fp32 stream
__device__ __forceinline__ float ldin(const void* p, size_t i, int bf) {
  return bf ? __bfloat162float(((const __hip_bfloat16*)p)[i])
            : ((const float*)p)[i];
}

__device__ __forceinline__ float4 ldin4(const void* p, size_t i4, int bf) {
  if (bf) {
    union { uint2 u; __hip_bfloat16 e[4]; } v;
    v.u = *(const uint2*)((const __hip_bfloat16*)p + i4 * 4);
    return make_float4(__bfloat162float(v.e[0]), __bfloat162float(v.e[1]),
                       __bfloat162float(v.e[2]), __bfloat162float(v.e[3]));
  }
  return ((const float4*)p)[i4];
}

// ---------------------------------------------------------------------------
// Dtype flag from ln1_g (== ones(768)).
// ---------------------------------------------------------------------------
__global__ void k_flag(const void* __restrict__ g, int* __restrict__ flag) {
  if (threadIdx.x == 0 && blockIdx.x == 0) {
    uint32_t w = *(const uint32_t*)g;
    *flag = ((w & 0xFFFFu) == 0x3F80u) ? 1 : 0;
  }
}

// ---------------------------------------------------------------------------
// Embedding
// ---------------------------------------------------------------------------
__global__ __launch_bounds__(256) void k_embed(
    const void* __restrict__ img, const void* __restrict__ cls,
    const void* __restrict__ pos, float* __restrict__ X,
    const int* __restrict__ dflag)
{
  const int bf = *dflag;
  size_t idx4 = (size_t)blockIdx.x * 256 + threadIdx.x;   // 12608*192 total
  if (idx4 >= (size_t)12608 * 192) return;
  int d4 = (int)(idx4 % 192);
  int row = (int)(idx4 / 192);
  int b = row / 197, s = row % 197;
  float4 base = (s == 0) ? ldin4(cls, d4, bf)
                         : ldin4(img, (size_t)(b * 196 + s - 1) * 192 + d4, bf);
  float4 p = ldin4(pos, (size_t)s * 192 + d4, bf);
  ((float4*)X)[idx4] = make_float4(base.x + p.x, base.y + p.y, base.z + p.z, base.w + p.w);
}

// ---------------------------------------------------------------------------
// Tiled transpose pack
// ---------------------------------------------------------------------------
__global__ __launch_bounds__(256) void k_packT(
    const void* __restrict__ in, __hip_bfloat16* __restrict__ out,
    int K, int N, int NR, const int* __restrict__ dflag)
{
  __shared__ float t[32][33];
  const int bf = *dflag;
  int ktiles = (K + 31) >> 5;
  int k0 = (blockIdx.x % ktiles) << 5;
  int n0 = (blockIdx.x / ktiles) << 5;
  int tx = threadIdx.x & 31, ty = threadIdx.x >> 5;   // 32 x 8
#pragma unroll
  for (int i = 0; i < 32; i += 8) {
    int k = k0 + ty + i, n = n0 + tx;
    t[ty + i][tx] = (k < K && n < N) ? ldin(in, (size_t)k * N + n, bf) : 0.f;
  }
  __syncthreads();
#pragma unroll
  for (int i = 0; i < 32; i += 8) {
    int n = n0 + ty + i, k = k0 + tx;
    if (n < NR && k < K)
      out[(size_t)n * K + k] = __float2bfloat16(t[tx][ty + i]);
  }
}

// ---------------------------------------------------------------------------
// cls-row pack for the head
// ---------------------------------------------------------------------------
__global__ __launch_bounds__(256) void k_packcls(
    const float* __restrict__ X, __hip_bfloat16* __restrict__ xcls)
{
  int idx = blockIdx.x * 256 + threadIdx.x;   // 128*768
  if (idx >= 128 * 768) return;
  int r = idx / 768, d = idx % 768;
  float v = (r < 64) ? X[(size_t)r * 197 * 768 + d] : 0.f;
  xcls[idx] = __float2bfloat16(v);
}

// ---------------------------------------------------------------------------
// LayerNorm
// ---------------------------------------------------------------------------
__global__ __launch_bounds__(256) void k_ln(
    const float* __restrict__ X, const void* __restrict__ g,
    const void* __restrict__ b, __hip_bfloat16* __restrict__ Y, int rows,
    const int* __restrict__ dflag)
{
  const int bf = *dflag;
  int wave = threadIdx.x >> 6, lane = threadIdx.x & 63;
  int row = blockIdx.x * 4 + wave;
  if (row >= rows) return;
  const float4* xr = (const float4*)(X + (size_t)row * 768);
  float4 v[3];
  float s = 0.f;
#pragma unroll
  for (int i = 0; i < 3; i++) {
    v[i] = xr[lane + i * 64];
    s += v[i].x + v[i].y + v[i].z + v[i].w;
  }
#pragma unroll
  for (int m = 1; m < 64; m <<= 1) s += __shfl_xor(s, m, 64);
  float mu = s * (1.f / 768.f);
  float q = 0.f;
#pragma unroll
  for (int i = 0; i < 3; i++) {
    float dx = v[i].x - mu, dy = v[i].y - mu, dz = v[i].z - mu, dw = v[i].w - mu;
    q += dx * dx + dy * dy + dz * dz + dw * dw;
  }
#pragma unroll
  for (int m = 1; m < 64; m <<= 1) q += __shfl_xor(q, m, 64);
  float rs = rsqrtf(q * (1.f / 768.f) + 1e-5f);
  uint2* yr = (uint2*)(Y + (size_t)row * 768);
#pragma unroll
  for (int i = 0; i < 3; i++) {
    int i4 = lane + i * 64;
    float4 gv = ldin4(g, i4, bf);
    float4 bv = ldin4(b, i4, bf);
    union { uint2 u; __hip_bfloat16 e[4]; } o;
    o.e[0] = __float2bfloat16((v[i].x - mu) * rs * gv.x + bv.x);
    o.e[1] = __float2bfloat16((v[i].y - mu) * rs * gv.y + bv.y);
    o.e[2] = __float2bfloat16((v[i].z - mu) * rs * gv.z + bv.z);
    o.e[3] = __float2bfloat16((v[i].w - mu) * rs * gv.w + bv.w);
    yr[i4] = o.u;
  }
}

// ---------------------------------------------------------------------------
// GEMM: C[M][N] = A[M][K] * Bt[N][K]^T.  512 threads, 128x256 block tile,
// BK=64, 8 waves each 64x64 (2x4 wave grid), R5's 2-barrier single-buffer
// K-loop, XOR-swizzled conflict-free LDS, XCD-slab mapping.
// EPI 0: bf16; 1: +bias relu bf16; 2: +bias +Res fp32; 3: head
// ORDER 0: bn-outer/bm-inner; 1: bm-outer/bn-inner; 2: legacy linear
// Requires K % 64 == 0.
// ---------------------------------------------------------------------------
template <int EPI, int ORDER>
__global__ __launch_bounds__(512, 2) void k_gemm(
    const __hip_bfloat16* __restrict__ A, const __hip_bfloat16* __restrict__ Bt,
    const void* __restrict__ bias, const float* __restrict__ Res,
    void* __restrict__ Cout, int K, int N, int Mstore, int ntiles, int mtiles,
    const int* __restrict__ dflag)
{
  __shared__ __align__(16) __hip_bfloat16 As[128 * 64];   // 16 KB
  __shared__ __align__(16) __hip_bfloat16 Bs[256 * 64];   // 32 KB

  int bm, bn;
  if (ORDER == 2) {
    bm = blockIdx.x / ntiles; bn = blockIdx.x % ntiles;
  } else {
    const int xcd = blockIdx.x & 7;
    const int i = blockIdx.x >> 3;
    if (ORDER == 0) { bn = i / 13; bm = xcd * 13 + (i % 13); }
    else            { bm = xcd * 13 + i / ntiles; bn = i % ntiles; }
    if (bm >= mtiles) return;
  }

  const int bf = (EPI == 0) ? 0 : *dflag;
  const int tid = threadIdx.x;
  const int m0 = bm * 128, n0 = bn * 256;
  const int wave = tid >> 6, lane = tid & 63;
  const int wm = (wave >> 2) * 64, wn = (wave & 3) * 64;
  const int qd = lane >> 4, l16 = lane & 15;

  // Staging: chunk q covers (row = q>>3, slot c = q&7); global col fetched is
  // c ^ (row&7). Threads cover q = tid + 512*g; (q>>3)&7 == (tid>>3)&7.
  const int r0 = tid >> 3;                                // 0..63
  const int kk0 = (((tid & 7) ^ (r0 & 7))) * 8;
  const __hip_bfloat16* Agp = A + (size_t)(m0 + r0) * K + kk0;
  const __hip_bfloat16* Bgp = Bt + (size_t)(n0 + r0) * K + kk0;

  f32x4 acc[4][4] = {};

  for (int k0 = 0; k0 < K; k0 += 64) {
#pragma unroll
    for (int g = 0; g < 2; g++)          // A: 128 rows
      gld_lds16(Agp + (size_t)(64 * g) * K, &As[(tid + 512 * g) * 8]);
#pragma unroll
    for (int g = 0; g < 4; g++)          // B: 256 rows
      gld_lds16(Bgp + (size_t)(64 * g) * K, &Bs[(tid + 512 * g) * 8]);
    Agp += 64; Bgp += 64;
    __syncthreads();   // drains vmcnt -> tiles visible
#pragma unroll
    for (int h = 0; h < 2; h++) {        // two 32-wide k-slices
      bf16x8 af[4], bfr[4];
#pragma unroll
      for (int i = 0; i < 4; i++) {
        int row = wm + i * 16 + l16;
        int ch = (h * 4 + qd) ^ (row & 7);
        af[i] = *(const bf16x8*)&As[row * 64 + ch * 8];
      }
#pragma unroll
      for (int j = 0; j < 4; j++) {
        int row = wn + j * 16 + l16;
        int ch = (h * 4 + qd) ^ (row & 7);
        bfr[j] = *(const bf16x8*)&Bs[row * 64 + ch * 8];
      }
#pragma unroll
      for (int i = 0; i < 4; i++)
#pragma unroll
        for (int j = 0; j < 4; j++)
          acc[i][j] = __builtin_amdgcn_mfma_f32_16x16x32_bf16(af[i], bfr[j], acc[i][j], 0, 0, 0);
    }
    __syncthreads();   // all reads done before next staging
  }

  // C/D layout: col = lane&15, row = (lane>>4)*4 + reg   [m89-verified]
#pragma unroll
  for (int i = 0; i < 4; i++) {
#pragma unroll
    for (int r = 0; r < 4; r++) {
      int gr = m0 + wm + i * 16 + qd * 4 + r;
      if (gr < Mstore) {
#pragma unroll
        for (int j = 0; j < 4; j++) {
          int gc = n0 + wn + j * 16 + l16;
          float v = acc[i][j][r];
          if (EPI == 0) {
            ((__hip_bfloat16*)Cout)[(size_t)gr * N + gc] = __float2bfloat16(v);
          } else if (EPI == 1) {
            v += ldin(bias, gc, bf);
            v = v > 0.f ? v : 0.f;
            ((__hip_bfloat16*)Cout)[(size_t)gr * N + gc] = __float2bfloat16(v);
          } else if (EPI == 2) {
            v += ldin(bias, gc, bf) + Res[(size_t)gr * N + gc];
            ((float*)Cout)[(size_t)gr * N + gc] = v;
          } else {                       // EPI == 3: head
            if (gc < N) {
              v += ldin(bias, gc, bf);
              if (bf) ((__hip_bfloat16*)Cout)[(size_t)gr * N + gc] = __float2bfloat16(v);
              else    ((float*)Cout)[(size_t)gr * N + gc] = v;
            }
          }
        }
      }
    }
  }
}

// ---------------------------------------------------------------------------
// Fused attention (flash-style) — unchanged.
// ---------------------------------------------------------------------------
__global__ __launch_bounds__(256, 2) void k_attn(
    const __hip_bfloat16* __restrict__ qkv,   // [12608][2304] q|k|v
    const float* __restrict__ X, float* __restrict__ Aout)
{
  const int half = blockIdx.x & 1;
  const int bh = blockIdx.x >> 1;
  const int b = bh / 12, h = bh % 12;
  const size_t tokbase = (size_t)b * 197;

  __shared__ __align__(16) __hip_bfloat16 Ks[128 * 68];      // K[j][d], stride 68
  __shared__ __align__(16) __hip_bfloat16 Vt[64 * 132];      // V^T[d][j], stride 132
  __shared__ __align__(16) __hip_bfloat16 Ps[4][16 * 132];   // per-wave P tile

  const int tid = threadIdx.x;
  const int wave = tid >> 6, lane = tid & 63;
  const int qd = lane >> 4, l16 = lane & 15;

  const int tbase = half * 7;
  const int tcnt = half ? 6 : 7;
  const int mt[2] = { tbase + wave, tbase + wave + 4 };
  const int nmt = (wave + 4 < tcnt) ? 2 : 1;

  f32x4 Ofr[2][4] = {};           // [mtile][dtile], rows = qd*4+reg
  float mrun[2][4], lrun[2][4];
#pragma unroll
  for (int i = 0; i < 2; i++)
#pragma unroll
    for (int r = 0; r < 4; r++) { mrun[i][r] = -1e30f; lrun[i][r] = 0.f; }

  for (int jt = 0; jt < 2; jt++) {
    const int j0 = jt * 128;
    for (int c = tid; c < 128 * 16; c += 256) {
      int j = c >> 4, ch = (c & 15) * 4;
      const __hip_bfloat16* ksrc = qkv + (tokbase + j0 + j) * 2304 + 768 + h * 64 + ch;
      *(uint2*)&Ks[j * 68 + ch] = *(const uint2*)ksrc;
      const __hip_bfloat16* vsrc = qkv + (tokbase + j0 + j) * 2304 + 1536 + h * 64 + ch;
      union { uint2 u; __hip_bfloat16 e[4]; } vv;
      vv.u = *(const uint2*)vsrc;
      bool jvalid = (j0 + j) < 197;
      __hip_bfloat16 zero = __float2bfloat16(0.f);
#pragma unroll
      for (int i = 0; i < 4; i++)
        Vt[(ch + i) * 132 + j] = jvalid ? vv.e[i] : zero;
    }
    __syncthreads();

#pragma unroll
    for (int im = 0; im < 2; im++) {
      if (im < nmt) {
        const int m0 = mt[im] * 16;
        const __hip_bfloat16* qsrc = qkv + (tokbase + m0 + l16) * 2304 + h * 64 + qd * 8;
        bf16x8 qa0 = *(const bf16x8*)qsrc;
        bf16x8 qa1 = *(const bf16x8*)(qsrc + 32);

        f32x4 sc[8];
#pragma unroll
        for (int nt = 0; nt < 8; nt++) {
          bf16x8 kb0 = lds_read8u(&Ks[(nt * 16 + l16) * 68 + qd * 8]);
          bf16x8 kb1 = lds_read8u(&Ks[(nt * 16 + l16) * 68 + 32 + qd * 8]);
          f32x4 t = {0.f, 0.f, 0.f, 0.f};
          t = __builtin_amdgcn_mfma_f32_16x16x32_bf16(qa0, kb0, t, 0, 0, 0);
          sc[nt] = __builtin_amdgcn_mfma_f32_16x16x32_bf16(qa1, kb1, t, 0, 0, 0);
        }

        // ---- online softmax (NaN-sanitized) ----
        float rmax[4];
#pragma unroll
        for (int r = 0; r < 4; r++) rmax[r] = mrun[im][r];
#pragma unroll
        for (int nt = 0; nt < 8; nt++) {
          int col = j0 + nt * 16 + l16;
          bool valid = col < 197;
#pragma unroll
          for (int r = 0; r < 4; r++) {
            float sv = valid ? fminf(fmaxf(sc[nt][r] * 0.125f, -1e30f), 1e30f) : -1e30f;
            sc[nt][r] = sv;
            rmax[r] = fmaxf(rmax[r], sv);
          }
        }
#pragma unroll
        for (int r = 0; r < 4; r++) {
          float v = rmax[r];
          v = fmaxf(v, __shfl_xor(v, 1, 64));
          v = fmaxf(v, __shfl_xor(v, 2, 64));
          v = fmaxf(v, __shfl_xor(v, 4, 64));
          v = fmaxf(v, __shfl_xor(v, 8, 64));
          rmax[r] = v;
        }
        float alpha[4], rsum[4];
#pragma unroll
        for (int r = 0; r < 4; r++) {
          alpha[r] = exp2f((mrun[im][r] - rmax[r]) * LOG2E);
          rsum[r] = 0.f;
        }
#pragma unroll
        for (int nt = 0; nt < 8; nt++) {
#pragma unroll
          for (int r = 0; r < 4; r++) {
            float p = exp2f((sc[nt][r] - rmax[r]) * LOG2E);
            rsum[r] += p;
            Ps[wave][(qd * 4 + r) * 132 + nt * 16 + l16] = __float2bfloat16(p);
          }
        }
#pragma unroll
        for (int r = 0; r < 4; r++) {
          float v = rsum[r];
          v += __shfl_xor(v, 1, 64);
          v += __shfl_xor(v, 2, 64);
          v += __shfl_xor(v, 4, 64);
          v += __shfl_xor(v, 8, 64);
          lrun[im][r] = lrun[im][r] * alpha[r] + v;
          mrun[im][r] = rmax[r];
#pragma unroll
          for (int dt = 0; dt < 4; dt++) Ofr[im][dt][r] *= alpha[r];
        }

#pragma unroll
        for (int kf = 0; kf < 4; kf++) {
          bf16x8 pa = lds_read8u(&Ps[wave][l16 * 132 + kf * 32 + qd * 8]);
#pragma unroll
          for (int dt = 0; dt < 4; dt++) {
            bf16x8 vb = lds_read8u(&Vt[(dt * 16 + l16) * 132 + kf * 32 + qd * 8]);
            Ofr[im][dt] = __builtin_amdgcn_mfma_f32_16x16x32_bf16(pa, vb, Ofr[im][dt], 0, 0, 0);
          }
        }
      }
    }
    __syncthreads();
  }

#pragma unroll
  for (int im = 0; im < 2; im++) {
    if (im < nmt) {
      const int m0 = mt[im] * 16;
#pragma unroll
      for (int r = 0; r < 4; r++) {
        int row = m0 + qd * 4 + r;
        if (row < 197) {
          float inv = 1.f / lrun[im][r];
          size_t gbase = (tokbase + row) * 768 + h * 64;
#pragma unroll
          for (int dt = 0; dt < 4; dt++) {
            int col = dt * 16 + l16;
            Aout[gbase + col] = X[gbase + col] + Ofr[im][dt][r] * inv;
          }
        }
      }
    }
  }
}

// ---------------------------------------------------------------------------
// Workspace layout: unchanged (total 188,157,952 bytes).
// ---------------------------------------------------------------------------
extern "C" void kernel_launch(void* const* d_in, const int* in_sizes, int n_in,
                              void* d_out, int out_size, void* d_ws, size_t ws_size,
                              hipStream_t stream)
{
  const void* image = d_in[0];
  const void* cls   = d_in[1];
  const void* pos   = d_in[2];
  const void* ln1g  = d_in[3];
  const void* ln1b  = d_in[4];
  const void* wq    = d_in[5];
  const void* wk    = d_in[6];
  const void* wv    = d_in[7];
  const void* ln2g  = d_in[8];
  const void* ln2b  = d_in[9];
  const void* w1    = d_in[10];
  const void* b1    = d_in[11];
  const void* w2    = d_in[12];
  const void* b2    = d_in[13];
  const void* hw    = d_in[14];
  const void* hb    = d_in[15];

  if (ws_size < 188157952ull) return;  // not enough scratch -> loud failure

  char* w = (char*)d_ws;
  __hip_bfloat16* xn    = (__hip_bfloat16*)(w);
  __hip_bfloat16* qkv   = (__hip_bfloat16*)(w + 19464192);
  __hip_bfloat16* hid   = qkv;  // disjoint lifetimes
  __hip_bfloat16* hwT   = qkv;  // reused after the loop
  __hip_bfloat16* xcls  = (__hip_bfloat16*)(w + 19464192 + 1572864);
  __hip_bfloat16* wqkvT = (__hip_bfloat16*)(w + 97320960);
  __hip_bfloat16* w1T   = (__hip_bfloat16*)(w + 100859904);
  __hip_bfloat16* w2T   = (__hip_bfloat16*)(w + 105578496);
  float* X              = (float*)(w + 110297088);
  float* A              = (float*)(w + 149225472);
  int* dflag            = (int*)(w + 188153856);

  k_flag<<<1, 64, 0, stream>>>(ln1g, dflag);
  k_packT<<<24 * 24, 256, 0, stream>>>(wq, wqkvT,              768,  768,  768, dflag);
  k_packT<<<24 * 24, 256, 0, stream>>>(wk, wqkvT +  768 * 768, 768,  768,  768, dflag);
  k_packT<<<24 * 24, 256, 0, stream>>>(wv, wqkvT + 1536 * 768, 768,  768,  768, dflag);
  k_packT<<<24 * 96, 256, 0, stream>>>(w1, w1T,                768, 3072, 3072, dflag);
  k_packT<<<96 * 24, 256, 0, stream>>>(w2, w2T,               3072,  768,  768, dflag);
  k_embed<<<9456, 256, 0, stream>>>(image, cls, pos, X, dflag);

  for (int l = 0; l < 4; l++) {
    k_ln<<<3152, 256, 0, stream>>>(X, ln1g, ln1b, xn, 12608, dflag);
    k_gemm<0,0><<<8 * 13 * 9, 512, 0, stream>>>(xn, wqkvT, (const void*)nullptr,
                                           (const float*)nullptr, qkv, 768, 2304, 12608, 9, 99, dflag);
    k_attn<<<1536, 256, 0, stream>>>(qkv, X, A);
    k_ln<<<3152, 256, 0, stream>>>(A, ln2g, ln2b, xn, 12608, dflag);
    k_gemm<1,0><<<8 * 13 * 12, 512, 0, stream>>>(xn, w1T, b1, (const float*)nullptr,
                                           hid, 768, 3072, 12608, 12, 99, dflag);
    k_gemm<2,1><<<8 * 13 * 3, 512, 0, stream>>>(hid, w2T, b2, A, X, 3072, 768, 12608, 3, 99, dflag);
  }

  // classifier head as MFMA GEMM (qkv region is free now)
  k_packT<<<24 * 32, 256, 0, stream>>>(hw, hwT, 768, 1000, 1024, dflag);
  k_packcls<<<384, 256, 0, stream>>>(X, xcls);
  k_gemm<3,2><<<4, 512, 0, stream>>>(xcls, hwT, hb, (const float*)nullptr,
                                   d_out, 768, 1000, 64, 4, 1, dflag);
}

// Round 9
// 1349.812 us; speedup vs baseline: 1.2549x; 1.0681x over previous
//
#include <hip/hip_runtime.h>
#include <hip/hip_bf16.h>
#include <stdint.h>

// ---------------------------------------------------------------------------
// ViT encoder (4 shared layers) for MI355X. Dtype-agnostic ingest, fp32
// residual stream in ws, bf16 MFMA (16x16x32) everywhere.
// R4: XOR-swizzled LDS staging + XCD-slab mapping (conflicts -> 0).
// R5: BK=64, 256t, 2-barrier single-buffer loop  <- proven best (1382 us)
// R6/R7/R8: fat-acc / dbuf / 512t-wide all regressed -> reverted.
// R9: R5 GEMM restored; MLP2 gets MT=64 tiles (64x128, grid 594->1200 blocks)
//     to fix its measured grid starvation (2.3 blocks/CU vs 4 resident-capable).
// ---------------------------------------------------------------------------

typedef __attribute__((ext_vector_type(8))) short bf16x8;   // 8 bf16 = 4 VGPRs
typedef __attribute__((ext_vector_type(4))) short bf16x4;   // 8 bytes
typedef __attribute__((ext_vector_type(4))) float f32x4;

#define LOG2E 1.44269504088896340736f

typedef const __attribute__((address_space(1))) uint32_t gas_u32;
typedef __attribute__((address_space(3))) uint32_t las_u32;

__device__ __forceinline__ void gld_lds16(const void* g, void* l) {
  __builtin_amdgcn_global_load_lds((gas_u32*)g, (las_u32*)l, 16, 0, 0);
}

__device__ __forceinline__ bf16x8 lds_read8u(const __hip_bfloat16* p) {
  union { bf16x4 h[2]; bf16x8 v; } u;
  u.h[0] = *(const bf16x4*)p;
  u.h[1] = *(const bf16x4*)(p + 4);
  return u.v;
}

// flag-aware raw-input load: bf==1 -> bf16 stream, bf==0 -> fp32 stream
__device__ __forceinline__ float ldin(const void* p, size_t i, int bf) {
  return bf ? __bfloat162float(((const __hip_bfloat16*)p)[i])
            : ((const float*)p)[i];
}

__device__ __forceinline__ float4 ldin4(const void* p, size_t i4, int bf) {
  if (bf) {
    union { uint2 u; __hip_bfloat16 e[4]; } v;
    v.u = *(const uint2*)((const __hip_bfloat16*)p + i4 * 4);
    return make_float4(__bfloat162float(v.e[0]), __bfloat162float(v.e[1]),
                       __bfloat162float(v.e[2]), __bfloat162float(v.e[3]));
  }
  return ((const float4*)p)[i4];
}

// ---------------------------------------------------------------------------
// Dtype flag from ln1_g (== ones(768)).
// ---------------------------------------------------------------------------
__global__ void k_flag(const void* __restrict__ g, int* __restrict__ flag) {
  if (threadIdx.x == 0 && blockIdx.x == 0) {
    uint32_t w = *(const uint32_t*)g;
    *flag = ((w & 0xFFFFu) == 0x3F80u) ? 1 : 0;
  }
}

// ---------------------------------------------------------------------------
// Embedding
// ---------------------------------------------------------------------------
__global__ __launch_bounds__(256) void k_embed(
    const void* __restrict__ img, const void* __restrict__ cls,
    const void* __restrict__ pos, float* __restrict__ X,
    const int* __restrict__ dflag)
{
  const int bf = *dflag;
  size_t idx4 = (size_t)blockIdx.x * 256 + threadIdx.x;   // 12608*192 total
  if (idx4 >= (size_t)12608 * 192) return;
  int d4 = (int)(idx4 % 192);
  int row = (int)(idx4 / 192);
  int b = row / 197, s = row % 197;
  float4 base = (s == 0) ? ldin4(cls, d4, bf)
                         : ldin4(img, (size_t)(b * 196 + s - 1) * 192 + d4, bf);
  float4 p = ldin4(pos, (size_t)s * 192 + d4, bf);
  ((float4*)X)[idx4] = make_float4(base.x + p.x, base.y + p.y, base.z + p.z, base.w + p.w);
}

// ---------------------------------------------------------------------------
// Tiled transpose pack
// ---------------------------------------------------------------------------
__global__ __launch_bounds__(256) void k_packT(
    const void* __restrict__ in, __hip_bfloat16* __restrict__ out,
    int K, int N, int NR, const int* __restrict__ dflag)
{
  __shared__ float t[32][33];
  const int bf = *dflag;
  int ktiles = (K + 31) >> 5;
  int k0 = (blockIdx.x % ktiles) << 5;
  int n0 = (blockIdx.x / ktiles) << 5;
  int tx = threadIdx.x & 31, ty = threadIdx.x >> 5;   // 32 x 8
#pragma unroll
  for (int i = 0; i < 32; i += 8) {
    int k = k0 + ty + i, n = n0 + tx;
    t[ty + i][tx] = (k < K && n < N) ? ldin(in, (size_t)k * N + n, bf) : 0.f;
  }
  __syncthreads();
#pragma unroll
  for (int i = 0; i < 32; i += 8) {
    int n = n0 + ty + i, k = k0 + tx;
    if (n < NR && k < K)
      out[(size_t)n * K + k] = __float2bfloat16(t[tx][ty + i]);
  }
}

// ---------------------------------------------------------------------------
// cls-row pack for the head
// ---------------------------------------------------------------------------
__global__ __launch_bounds__(256) void k_packcls(
    const float* __restrict__ X, __hip_bfloat16* __restrict__ xcls)
{
  int idx = blockIdx.x * 256 + threadIdx.x;   // 128*768
  if (idx >= 128 * 768) return;
  int r = idx / 768, d = idx % 768;
  float v = (r < 64) ? X[(size_t)r * 197 * 768 + d] : 0.f;
  xcls[idx] = __float2bfloat16(v);
}

// ---------------------------------------------------------------------------
// LayerNorm
// ---------------------------------------------------------------------------
__global__ __launch_bounds__(256) void k_ln(
    const float* __restrict__ X, const void* __restrict__ g,
    const void* __restrict__ b, __hip_bfloat16* __restrict__ Y, int rows,
    const int* __restrict__ dflag)
{
  const int bf = *dflag;
  int wave = threadIdx.x >> 6, lane = threadIdx.x & 63;
  int row = blockIdx.x * 4 + wave;
  if (row >= rows) return;
  const float4* xr = (const float4*)(X + (size_t)row * 768);
  float4 v[3];
  float s = 0.f;
#pragma unroll
  for (int i = 0; i < 3; i++) {
    v[i] = xr[lane + i * 64];
    s += v[i].x + v[i].y + v[i].z + v[i].w;
  }
#pragma unroll
  for (int m = 1; m < 64; m <<= 1) s += __shfl_xor(s, m, 64);
  float mu = s * (1.f / 768.f);
  float q = 0.f;
#pragma unroll
  for (int i = 0; i < 3; i++) {
    float dx = v[i].x - mu, dy = v[i].y - mu, dz = v[i].z - mu, dw = v[i].w - mu;
    q += dx * dx + dy * dy + dz * dz + dw * dw;
  }
#pragma unroll
  for (int m = 1; m < 64; m <<= 1) q += __shfl_xor(q, m, 64);
  float rs = rsqrtf(q * (1.f / 768.f) + 1e-5f);
  uint2* yr = (uint2*)(Y + (size_t)row * 768);
#pragma unroll
  for (int i = 0; i < 3; i++) {
    int i4 = lane + i * 64;
    float4 gv = ldin4(g, i4, bf);
    float4 bv = ldin4(b, i4, bf);
    union { uint2 u; __hip_bfloat16 e[4]; } o;
    o.e[0] = __float2bfloat16((v[i].x - mu) * rs * gv.x + bv.x);
    o.e[1] = __float2bfloat16((v[i].y - mu) * rs * gv.y + bv.y);
    o.e[2] = __float2bfloat16((v[i].z - mu) * rs * gv.z + bv.z);
    o.e[3] = __float2bfloat16((v[i].w - mu) * rs * gv.w + bv.w);
    yr[i4] = o.u;
  }
}

// ---------------------------------------------------------------------------
// GEMM: C[M][N] = A[M][K] * Bt[N][K]^T.  MT x 128 block tile, BK=64,
// 256 threads, R5's 2-barrier single-buffer K-loop, XOR-swizzled
// conflict-free LDS, XCD-slab mapping.
// MT=128: 4 waves each 64x64 (acc 4x4).  MT=64: 4 waves each 64x32 (acc 4x2)
//         — doubles the grid for small-N GEMMs (MLP2 occupancy fix).
// EPI 0: bf16; 1: +bias relu bf16; 2: +bias +Res fp32; 3: head
// ORDER 0: bn-outer/bm-inner; 1: bm-outer/bn-inner; 2: legacy linear
// Requires K % 64 == 0.
// ---------------------------------------------------------------------------
template <int EPI, int ORDER, int MT>
__global__ __launch_bounds__(256, 2) void k_gemm(
    const __hip_bfloat16* __restrict__ A, const __hip_bfloat16* __restrict__ Bt,
    const void* __restrict__ bias, const float* __restrict__ Res,
    void* __restrict__ Cout, int K, int N, int Mstore, int ntiles, int mtiles,
    int mslab, const int* __restrict__ dflag)
{
  __shared__ __align__(16) __hip_bfloat16 As[MT * 64];    // 16 or 8 KB
  __shared__ __align__(16) __hip_bfloat16 Bs[128 * 64];   // 16 KB
  constexpr int JT = (MT == 128) ? 4 : 2;
  constexpr int AG = MT / 32;   // A staging groups

  int bm, bn;
  if (ORDER == 2) {
    bm = blockIdx.x / ntiles; bn = blockIdx.x % ntiles;
  } else {
    const int xcd = blockIdx.x & 7;
    const int i = blockIdx.x >> 3;
    if (ORDER == 0) { bn = i / mslab; bm = xcd * mslab + (i % mslab); }
    else            { bm = xcd * mslab + i / ntiles; bn = i % ntiles; }
    if (bm >= mtiles) return;
  }

  const int bf = (EPI == 0) ? 0 : *dflag;
  const int tid = threadIdx.x;
  const int m0 = bm * MT, n0 = bn * 128;
  const int wave = tid >> 6, lane = tid & 63;
  const int wm = (MT == 128) ? (wave >> 1) * 64 : 0;
  const int wn = (MT == 128) ? (wave & 1) * 64 : wave * 32;
  const int qd = lane >> 4, l16 = lane & 15;

  // Staging: chunk q covers (row = q>>3, slot c = q&7); global col fetched is
  // c ^ (row&7). Threads cover q = tid + 256*g; (q>>3)&7 == (tid>>3)&7.
  const int r0 = tid >> 3;                                // 0..31
  const int kk0 = (((tid & 7) ^ (r0 & 7))) * 8;
  const __hip_bfloat16* Agp = A + (size_t)(m0 + r0) * K + kk0;
  const __hip_bfloat16* Bgp = Bt + (size_t)(n0 + r0) * K + kk0;

  f32x4 acc[4][JT] = {};

  for (int k0 = 0; k0 < K; k0 += 64) {
#pragma unroll
    for (int g = 0; g < AG; g++)
      gld_lds16(Agp + (size_t)(32 * g) * K, &As[(tid + 256 * g) * 8]);
#pragma unroll
    for (int g = 0; g < 4; g++)
      gld_lds16(Bgp + (size_t)(32 * g) * K, &Bs[(tid + 256 * g) * 8]);
    Agp += 64; Bgp += 64;
    __syncthreads();   // drains vmcnt -> tiles visible
#pragma unroll
    for (int h = 0; h < 2; h++) {          // two 32-wide k-slices
      bf16x8 af[4], bfr[JT];
#pragma unroll
      for (int i = 0; i < 4; i++) {
        int row = wm + i * 16 + l16;
        int ch = (h * 4 + qd) ^ (row & 7);
        af[i] = *(const bf16x8*)&As[row * 64 + ch * 8];
      }
#pragma unroll
      for (int j = 0; j < JT; j++) {
        int row = wn + j * 16 + l16;
        int ch = (h * 4 + qd) ^ (row & 7);
        bfr[j] = *(const bf16x8*)&Bs[row * 64 + ch * 8];
      }
#pragma unroll
      for (int i = 0; i < 4; i++)
#pragma unroll
        for (int j = 0; j < JT; j++)
          acc[i][j] = __builtin_amdgcn_mfma_f32_16x16x32_bf16(af[i], bfr[j], acc[i][j], 0, 0, 0);
    }
    __syncthreads();   // all reads done before next staging
  }

  // C/D layout: col = lane&15, row = (lane>>4)*4 + reg   [m89-verified]
#pragma unroll
  for (int i = 0; i < 4; i++) {
#pragma unroll
    for (int r = 0; r < 4; r++) {
      int gr = m0 + wm + i * 16 + qd * 4 + r;
      if (gr < Mstore) {
#pragma unroll
        for (int j = 0; j < JT; j++) {
          int gc = n0 + wn + j * 16 + l16;
          float v = acc[i][j][r];
          if (EPI == 0) {
            ((__hip_bfloat16*)Cout)[(size_t)gr * N + gc] = __float2bfloat16(v);
          } else if (EPI == 1) {
            v += ldin(bias, gc, bf);
            v = v > 0.f ? v : 0.f;
            ((__hip_bfloat16*)Cout)[(size_t)gr * N + gc] = __float2bfloat16(v);
          } else if (EPI == 2) {
            v += ldin(bias, gc, bf) + Res[(size_t)gr * N + gc];
            ((float*)Cout)[(size_t)gr * N + gc] = v;
          } else {                       // EPI == 3: head
            if (gc < N) {
              v += ldin(bias, gc, bf);
              if (bf) ((__hip_bfloat16*)Cout)[(size_t)gr * N + gc] = __float2bfloat16(v);
              else    ((float*)Cout)[(size_t)gr * N + gc] = v;
            }
          }
        }
      }
    }
  }
}

// ---------------------------------------------------------------------------
// Fused attention (flash-style) — unchanged.
// ---------------------------------------------------------------------------
__global__ __launch_bounds__(256, 2) void k_attn(
    const __hip_bfloat16* __restrict__ qkv,   // [12608][2304] q|k|v
    const float* __restrict__ X, float* __restrict__ Aout)
{
  const int half = blockIdx.x & 1;
  const int bh = blockIdx.x >> 1;
  const int b = bh / 12, h = bh % 12;
  const size_t tokbase = (size_t)b * 197;

  __shared__ __align__(16) __hip_bfloat16 Ks[128 * 68];      // K[j][d], stride 68
  __shared__ __align__(16) __hip_bfloat16 Vt[64 * 132];      // V^T[d][j], stride 132
  __shared__ __align__(16) __hip_bfloat16 Ps[4][16 * 132];   // per-wave P tile

  const int tid = threadIdx.x;
  const int wave = tid >> 6, lane = tid & 63;
  const int qd = lane >> 4, l16 = lane & 15;

  const int tbase = half * 7;
  const int tcnt = half ? 6 : 7;
  const int mt[2] = { tbase + wave, tbase + wave + 4 };
  const int nmt = (wave + 4 < tcnt) ? 2 : 1;

  f32x4 Ofr[2][4] = {};           // [mtile][dtile], rows = qd*4+reg
  float mrun[2][4], lrun[2][4];
#pragma unroll
  for (int i = 0; i < 2; i++)
#pragma unroll
    for (int r = 0; r < 4; r++) { mrun[i][r] = -1e30f; lrun[i][r] = 0.f; }

  for (int jt = 0; jt < 2; jt++) {
    const int j0 = jt * 128;
    for (int c = tid; c < 128 * 16; c += 256) {
      int j = c >> 4, ch = (c & 15) * 4;
      const __hip_bfloat16* ksrc = qkv + (tokbase + j0 + j) * 2304 + 768 + h * 64 + ch;
      *(uint2*)&Ks[j * 68 + ch] = *(const uint2*)ksrc;
      const __hip_bfloat16* vsrc = qkv + (tokbase + j0 + j) * 2304 + 1536 + h * 64 + ch;
      union { uint2 u; __hip_bfloat16 e[4]; } vv;
      vv.u = *(const uint2*)vsrc;
      bool jvalid = (j0 + j) < 197;
      __hip_bfloat16 zero = __float2bfloat16(0.f);
#pragma unroll
      for (int i = 0; i < 4; i++)
        Vt[(ch + i) * 132 + j] = jvalid ? vv.e[i] : zero;
    }
    __syncthreads();

#pragma unroll
    for (int im = 0; im < 2; im++) {
      if (im < nmt) {
        const int m0 = mt[im] * 16;
        const __hip_bfloat16* qsrc = qkv + (tokbase + m0 + l16) * 2304 + h * 64 + qd * 8;
        bf16x8 qa0 = *(const bf16x8*)qsrc;
        bf16x8 qa1 = *(const bf16x8*)(qsrc + 32);

        f32x4 sc[8];
#pragma unroll
        for (int nt = 0; nt < 8; nt++) {
          bf16x8 kb0 = lds_read8u(&Ks[(nt * 16 + l16) * 68 + qd * 8]);
          bf16x8 kb1 = lds_read8u(&Ks[(nt * 16 + l16) * 68 + 32 + qd * 8]);
          f32x4 t = {0.f, 0.f, 0.f, 0.f};
          t = __builtin_amdgcn_mfma_f32_16x16x32_bf16(qa0, kb0, t, 0, 0, 0);
          sc[nt] = __builtin_amdgcn_mfma_f32_16x16x32_bf16(qa1, kb1, t, 0, 0, 0);
        }

        // ---- online softmax (NaN-sanitized) ----
        float rmax[4];
#pragma unroll
        for (int r = 0; r < 4; r++) rmax[r] = mrun[im][r];
#pragma unroll
        for (int nt = 0; nt < 8; nt++) {
          int col = j0 + nt * 16 + l16;
          bool valid = col < 197;
#pragma unroll
          for (int r = 0; r < 4; r++) {
            float sv = valid ? fminf(fmaxf(sc[nt][r] * 0.125f, -1e30f), 1e30f) : -1e30f;
            sc[nt][r] = sv;
            rmax[r] = fmaxf(rmax[r], sv);
          }
        }
#pragma unroll
        for (int r = 0; r < 4; r++) {
          float v = rmax[r];
          v = fmaxf(v, __shfl_xor(v, 1, 64));
          v = fmaxf(v, __shfl_xor(v, 2, 64));
          v = fmaxf(v, __shfl_xor(v, 4, 64));
          v = fmaxf(v, __shfl_xor(v, 8, 64));
          rmax[r] = v;
        }
        float alpha[4], rsum[4];
#pragma unroll
        for (int r = 0; r < 4; r++) {
          alpha[r] = exp2f((mrun[im][r] - rmax[r]) * LOG2E);
          rsum[r] = 0.f;
        }
#pragma unroll
        for (int nt = 0; nt < 8; nt++) {
#pragma unroll
          for (int r = 0; r < 4; r++) {
            float p = exp2f((sc[nt][r] - rmax[r]) * LOG2E);
            rsum[r] += p;
            Ps[wave][(qd * 4 + r) * 132 + nt * 16 + l16] = __float2bfloat16(p);
          }
        }
#pragma unroll
        for (int r = 0; r < 4; r++) {
          float v = rsum[r];
          v += __shfl_xor(v, 1, 64);
          v += __shfl_xor(v, 2, 64);
          v += __shfl_xor(v, 4, 64);
          v += __shfl_xor(v, 8, 64);
          lrun[im][r] = lrun[im][r] * alpha[r] + v;
          mrun[im][r] = rmax[r];
#pragma unroll
          for (int dt = 0; dt < 4; dt++) Ofr[im][dt][r] *= alpha[r];
        }

#pragma unroll
        for (int kf = 0; kf < 4; kf++) {
          bf16x8 pa = lds_read8u(&Ps[wave][l16 * 132 + kf * 32 + qd * 8]);
#pragma unroll
          for (int dt = 0; dt < 4; dt++) {
            bf16x8 vb = lds_read8u(&Vt[(dt * 16 + l16) * 132 + kf * 32 + qd * 8]);
            Ofr[im][dt] = __builtin_amdgcn_mfma_f32_16x16x32_bf16(pa, vb, Ofr[im][dt], 0, 0, 0);
          }
        }
      }
    }
    __syncthreads();
  }

#pragma unroll
  for (int im = 0; im < 2; im++) {
    if (im < nmt) {
      const int m0 = mt[im] * 16;
#pragma unroll
      for (int r = 0; r < 4; r++) {
        int row = m0 + qd * 4 + r;
        if (row < 197) {
          float inv = 1.f / lrun[im][r];
          size_t gbase = (tokbase + row) * 768 + h * 64;
#pragma unroll
          for (int dt = 0; dt < 4; dt++) {
            int col = dt * 16 + l16;
            Aout[gbase + col] = X[gbase + col] + Ofr[im][dt][r] * inv;
          }
        }
      }
    }
  }
}

// ---------------------------------------------------------------------------
// Workspace layout: unchanged (total 188,157,952 bytes).
// ---------------------------------------------------------------------------
extern "C" void kernel_launch(void* const* d_in, const int* in_sizes, int n_in,
                              void* d_out, int out_size, void* d_ws, size_t ws_size,
                              hipStream_t stream)
{
  const void* image = d_in[0];
  const void* cls   = d_in[1];
  const void* pos   = d_in[2];
  const void* ln1g  = d_in[3];
  const void* ln1b  = d_in[4];
  const void* wq    = d_in[5];
  const void* wk    = d_in[6];
  const void* wv    = d_in[7];
  const void* ln2g  = d_in[8];
  const void* ln2b  = d_in[9];
  const void* w1    = d_in[10];
  const void* b1    = d_in[11];
  const void* w2    = d_in[12];
  const void* b2    = d_in[13];
  const void* hw    = d_in[14];
  const void* hb    = d_in[15];

  if (ws_size < 188157952ull) return;  // not enough scratch -> loud failure

  char* w = (char*)d_ws;
  __hip_bfloat16* xn    = (__hip_bfloat16*)(w);
  __hip_bfloat16* qkv   = (__hip_bfloat16*)(w + 19464192);
  __hip_bfloat16* hid   = qkv;  // disjoint lifetimes
  __hip_bfloat16* hwT   = qkv;  // reused after the loop
  __hip_bfloat16* xcls  = (__hip_bfloat16*)(w + 19464192 + 1572864);
  __hip_bfloat16* wqkvT = (__hip_bfloat16*)(w + 97320960);
  __hip_bfloat16* w1T   = (__hip_bfloat16*)(w + 100859904);
  __hip_bfloat16* w2T   = (__hip_bfloat16*)(w + 105578496);
  float* X              = (float*)(w + 110297088);
  float* A              = (float*)(w + 149225472);
  int* dflag            = (int*)(w + 188153856);

  k_flag<<<1, 64, 0, stream>>>(ln1g, dflag);
  k_packT<<<24 * 24, 256, 0, stream>>>(wq, wqkvT,              768,  768,  768, dflag);
  k_packT<<<24 * 24, 256, 0, stream>>>(wk, wqkvT +  768 * 768, 768,  768,  768, dflag);
  k_packT<<<24 * 24, 256, 0, stream>>>(wv, wqkvT + 1536 * 768, 768,  768,  768, dflag);
  k_packT<<<24 * 96, 256, 0, stream>>>(w1, w1T,                768, 3072, 3072, dflag);
  k_packT<<<96 * 24, 256, 0, stream>>>(w2, w2T,               3072,  768,  768, dflag);
  k_embed<<<9456, 256, 0, stream>>>(image, cls, pos, X, dflag);

  for (int l = 0; l < 4; l++) {
    k_ln<<<3152, 256, 0, stream>>>(X, ln1g, ln1b, xn, 12608, dflag);
    k_gemm<0,0,128><<<8 * 13 * 18, 256, 0, stream>>>(xn, wqkvT, (const void*)nullptr,
                                           (const float*)nullptr, qkv, 768, 2304, 12608, 18, 99, 13, dflag);
    k_attn<<<1536, 256, 0, stream>>>(qkv, X, A);
    k_ln<<<3152, 256, 0, stream>>>(A, ln2g, ln2b, xn, 12608, dflag);
    k_gemm<1,0,128><<<8 * 13 * 24, 256, 0, stream>>>(xn, w1T, b1, (const float*)nullptr,
                                           hid, 768, 3072, 12608, 24, 99, 13, dflag);
    k_gemm<2,1,64><<<8 * 25 * 6, 256, 0, stream>>>(hid, w2T, b2, A, X, 3072, 768, 12608, 6, 197, 25, dflag);
  }

  // classifier head as MFMA GEMM (qkv region is free now)
  k_packT<<<24 * 32, 256, 0, stream>>>(hw, hwT, 768, 1000, 1024, dflag);
  k_packcls<<<384, 256, 0, stream>>>(X, xcls);
  k_gemm<3,2,128><<<8, 256, 0, stream>>>(xcls, hwT, hb, (const float*)nullptr,
                                   d_out, 768, 1000, 64, 8, 1, 1, dflag);
}